// Round 10
// baseline (280.303 us; speedup 1.0000x reference)
//
#include <hip/hip_runtime.h>
#include <stdint.h>

#define T_TOKENS 4096
#define HID 1024
#define FFN 2048
#define NE 8

typedef __attribute__((ext_vector_type(8))) short bf16x8;
typedef __attribute__((ext_vector_type(4))) float f32x4;

__device__ __forceinline__ unsigned short f2bf(float f) {
  union { float f; uint32_t u; } v; v.f = f;
  uint32_t r = v.u + 0x7FFFu + ((v.u >> 16) & 1u);
  return (unsigned short)(r >> 16);
}

__device__ __forceinline__ uint32_t pack2(float a, float b) {
  return (uint32_t)f2bf(a) | ((uint32_t)f2bf(b) << 16);
}

__device__ __forceinline__ void gload16(const unsigned short* g, unsigned short* l) {
  __builtin_amdgcn_global_load_lds(
      (const __attribute__((address_space(1))) void*)(g),
      (__attribute__((address_space(3))) void*)(l), 16, 0, 0);
}

// XOR chunk swizzle for the gathered A tile [128 rows][32 k] bf16.
__device__ __forceinline__ int frag_off(int r, int g) {
  return r * 32 + ((g ^ ((r >> 1) & 3)) << 3);
}

// ---- ws layout ----
constexpr size_t XBF_OFF  = 0;                                       // 8 MB
constexpr size_t HBUF_OFF = (size_t)T_TOKENS * HID * 2;              // 32 MB
constexpr size_t TOKE_OFF = HBUF_OFF + (size_t)T_TOKENS * 2 * FFN * 2;
constexpr size_t TOKW_OFF = TOKE_OFF + (size_t)T_TOKENS * 2 * 4;
constexpr size_t CNT_OFF  = TOKW_OFF + (size_t)T_TOKENS * 2 * 4;
constexpr size_t OFF_OFF  = CNT_OFF + 64;
constexpr size_t LIST_OFF = OFF_OFF + 64;
constexpr size_t META_END = LIST_OFF + (size_t)NE * T_TOKENS * 4;    // ~40.2 MB
constexpr size_t PB1_OFF  = META_END;                                // 32 MB (ybuf reuses)
constexpr size_t PB2_OFF  = PB1_OFF + (size_t)NE * FFN * HID * 2;    // 32 MB
constexpr size_t PW2_OFF  = PB2_OFF + (size_t)NE * FFN * HID * 2;    // 32 MB
constexpr size_t WS_BIG   = PW2_OFF + (size_t)NE * HID * FFN * 2;    // ~136.2 MB
constexpr size_t YBUF_OFF = PB1_OFF;   // ybuf [8192][HID] f32; pb1 dead after gemm1b

// ---- pack w1/v1 into fragment-linear layout: [e][col/16][k/32][512] (validated r8) ----
__global__ __launch_bounds__(256) void pack_w1v1_kernel(const float* __restrict__ w1,
                                                        const float* __restrict__ v1,
                                                        unsigned short* __restrict__ pb1,
                                                        unsigned short* __restrict__ pb2) {
  int colblk = blockIdx.x;            // 0..127 (FFN/16)
  int kslab  = blockIdx.y;            // 0..7   (HID/128)
  int ez     = blockIdx.z;            // 0..15
  const float* src = (ez < NE) ? w1 : v1;
  unsigned short* dst = (ez < NE) ? pb1 : pb2;
  int e = ez & (NE - 1);
  __shared__ unsigned short lds[2048];
  int t = threadIdx.x;
  int c  = colblk * 16 + (t >> 4);
  int k0 = kslab * 128 + (t & 15) * 8;
  const float* sp = src + ((size_t)e * FFN + c) * HID + k0;
  float4 a = *(const float4*)sp;
  float4 b = *(const float4*)(sp + 4);
  uint4 o;
  o.x = pack2(a.x, a.y); o.y = pack2(a.z, a.w);
  o.z = pack2(b.x, b.y); o.w = pack2(b.z, b.w);
  int chunk = ((t & 15) >> 2) * 64 + ((t & 3) * 16 + (t >> 4));
  int pos = chunk ^ ((chunk >> 4) & 15);
  *(uint4*)(lds + pos * 8) = o;
  __syncthreads();
  int rpos = t ^ ((t >> 4) & 15);
  uint4 v = *(const uint4*)(lds + rpos * 8);
  unsigned short* dp = dst + (((size_t)e * (FFN / 16) + colblk) * (HID / 32) + kslab * 4) * 512 + t * 8;
  *(uint4*)dp = v;
}

// ---- pack w2 [e][k(FFN)][c(HID)] f32 -> [e][c/16][k/32][512] bf16 (validated r8) ----
__global__ __launch_bounds__(256) void pack_w2_kernel(const float* __restrict__ w2,
                                                      unsigned short* __restrict__ pw2) {
  int cb = blockIdx.x;   // 0..15
  int kb = blockIdx.y;   // 0..31
  int e  = blockIdx.z;
  __shared__ unsigned short s[64][68];
  int t = threadIdx.x;
  int tr = t >> 4, tc = (t & 15) * 4;
  const float* src = w2 + ((size_t)e * FFN + kb * 64) * HID + cb * 64;
#pragma unroll
  for (int i = 0; i < 4; ++i) {
    int k = tr + i * 16;
    float4 v = *(const float4*)(src + (size_t)k * HID + tc);
    s[k][tc + 0] = f2bf(v.x); s[k][tc + 1] = f2bf(v.y);
    s[k][tc + 2] = f2bf(v.z); s[k][tc + 3] = f2bf(v.w);
  }
  __syncthreads();
#pragma unroll
  for (int half = 0; half < 2; ++half) {
    int cid = t + half * 256;
    int colblk_l = cid >> 7;
    int ks_l = (cid >> 6) & 1;
    int lane = cid & 63;
    unsigned short tmp[8];
#pragma unroll
    for (int j = 0; j < 8; ++j)
      tmp[j] = s[ks_l * 32 + (lane >> 4) * 8 + j][colblk_l * 16 + (lane & 15)];
    uint4 o;
    o.x = tmp[0] | (tmp[1] << 16); o.y = tmp[2] | (tmp[3] << 16);
    o.z = tmp[4] | (tmp[5] << 16); o.w = tmp[6] | (tmp[7] << 16);
    unsigned short* dp = pw2 + (((size_t)e * (HID / 16) + cb * 4 + colblk_l) * (FFN / 32)
                                + kb * 2 + ks_l) * 512 + lane * 8;
    *(uint4*)dp = o;
  }
}

// ---- router (+ fused x->bf16 cast) ----
__global__ __launch_bounds__(256) void router_kernel(const float* __restrict__ x,
                                                     const float* __restrict__ rw,
                                                     int* __restrict__ tok_e,
                                                     float* __restrict__ tok_w,
                                                     unsigned short* __restrict__ xbf) {
  __shared__ float s_rw[NE * HID];
  int tid = threadIdx.x;
  for (int i = tid; i < NE * HID / 4; i += 256)
    ((float4*)s_rw)[i] = ((const float4*)rw)[i];
  __syncthreads();
  int wave = tid >> 6, lane = tid & 63;
  int t = blockIdx.x * 4 + wave;
  const float* xr = x + (size_t)t * HID;
  unsigned short* xbr = xbf + (size_t)t * HID;
  float acc[NE];
#pragma unroll
  for (int e = 0; e < NE; ++e) acc[e] = 0.0f;
  for (int c = 0; c < HID / 64; ++c) {
    int idx = c * 64 + lane;
    float xv = xr[idx];
    xbr[idx] = f2bf(xv);
#pragma unroll
    for (int e = 0; e < NE; ++e) acc[e] += xv * s_rw[e * HID + idx];
  }
#pragma unroll
  for (int e = 0; e < NE; ++e)
    for (int off = 32; off > 0; off >>= 1) acc[e] += __shfl_down(acc[e], off);
  if (lane == 0) {
    float m = acc[0];
#pragma unroll
    for (int e = 1; e < NE; ++e) m = fmaxf(m, acc[e]);
    float p[NE], Z = 0.0f;
#pragma unroll
    for (int e = 0; e < NE; ++e) { p[e] = expf(acc[e] - m); Z += p[e]; }
    int e0 = 0;
#pragma unroll
    for (int e = 1; e < NE; ++e) if (p[e] > p[e0]) e0 = e;
    int e1 = (e0 == 0) ? 1 : 0;
#pragma unroll
    for (int e = 0; e < NE; ++e) if (e != e0 && p[e] > p[e1]) e1 = e;
    float w0 = p[e0] / Z, w1 = p[e1] / Z;
    float nrm = w0 + w1;  // P_NORM = 1
    tok_e[t * 2] = e0; tok_e[t * 2 + 1] = e1;
    tok_w[t * 2] = w0 / nrm; tok_w[t * 2 + 1] = w1 / nrm;
  }
}

// ---- merged scatter + offsets (single block; LDS counters) ----
__global__ __launch_bounds__(1024) void scatter_offsets_kernel(
    const int* __restrict__ tok_e, int* __restrict__ counts,
    int* __restrict__ offs, int* __restrict__ lists) {
  __shared__ int c[NE];
  int tid = threadIdx.x;
  if (tid < NE) c[tid] = 0;
  __syncthreads();
  for (int p = tid; p < T_TOKENS * 2; p += 1024) {
    int e = tok_e[p];
    int pos = atomicAdd(&c[e], 1);
    lists[e * T_TOKENS + pos] = p;
  }
  __syncthreads();
  if (tid == 0) {
    int r = 0;
    for (int e = 0; e < NE; ++e) { counts[e] = c[e]; offs[e] = r; r += c[e]; }
  }
}

__global__ __launch_bounds__(256) void combine_kernel(const float* __restrict__ ybuf,
                                                      float* __restrict__ out) {
  int t = blockIdx.x;
  int c = threadIdx.x;
  const float4* y0 = (const float4*)(ybuf + (size_t)(2 * t) * HID);
  const float4* y1 = (const float4*)(ybuf + (size_t)(2 * t + 1) * HID);
  float4 a = y0[c], b = y1[c];
  float4 r; r.x = a.x + b.x; r.y = a.y + b.y; r.z = a.z + b.z; r.w = a.w + b.w;
  ((float4*)(out + (size_t)t * HID))[c] = r;
}

// ========== GEMM1: ring-3 counted-vmcnt. A swizzled-LDS, B1 packed->LDS, B2->regs ====
// 512 thr = 8 waves (2Mx4N, 64x32/wave), block 128x128. LDS 48 KB (3 slots x A+B1).
// Per tile: 4 vmem ops (2 gload_lds + 2 reg loads). Steady-state wait = vmcnt(8)
// (2 tiles in flight), raw s_barrier with memory clobber — NO vmcnt(0) drain.
__global__ __launch_bounds__(512) void gemm1b_kernel(
    const unsigned short* __restrict__ xbf,
    const unsigned short* __restrict__ pb1, const unsigned short* __restrict__ pb2,
    const int* __restrict__ counts, const int* __restrict__ offs,
    const int* __restrict__ lists, unsigned short* __restrict__ hbuf) {
  constexpr int ABUF = 128 * 32;   // 8 KB per slot
  constexpr int BBUF = 128 * 32;   // 8 KB per slot
  constexpr int NT = HID / 32;     // 32
  int nt = blockIdx.x, mt = blockIdx.y, e = blockIdx.z;
  int ne = counts[e];
  if (mt * 128 >= ne) return;
  __shared__ unsigned short s_a[3 * ABUF];
  __shared__ unsigned short s_b1[3 * BBUF];
  int tid = threadIdx.x;
  // A staging (gathered rows, XOR-swizzled chunks)
  int srow = tid >> 2, slot = tid & 3;
  int lchunk = slot ^ ((srow >> 1) & 3);
  const int* lst = lists + e * T_TOKENS + mt * 128;
  int tok = lst[(mt * 128 + srow < ne) ? srow : 0] >> 1;
  const unsigned short* aptr = xbf + (size_t)tok * HID + lchunk * 8;
  // B1 staging from fragment-linear pack (linear LDS, conflict-free reads)
  int g8 = tid >> 6, ln = tid & 63;
  const unsigned short* b1p =
      pb1 + ((size_t)(e * (FFN / 16) + nt * 8 + g8) * (HID / 32)) * 512 + ln * 8;

  int lane = tid & 63, wv = tid >> 6;
  int wm = (wv >> 2) * 64, wn = (wv & 3) * 32;
  int rl = lane & 15, g = lane >> 4;
  int aoff[4];
#pragma unroll
  for (int m = 0; m < 4; ++m) aoff[m] = frag_off(wm + m * 16 + rl, g);
  int b1off[2];
#pragma unroll
  for (int n = 0; n < 2; ++n) b1off[n] = (((wv & 3) * 2 + n) * 64 + lane) * 8;
  size_t cb2 = (size_t)e * (FFN / 16) + nt * 8 + (wv & 3) * 2;
  const unsigned short* p2_0 = pb2 + (cb2 + 0) * (HID / 32) * 512 + lane * 8;
  const unsigned short* p2_1 = pb2 + (cb2 + 1) * (HID / 32) * 512 + lane * 8;

  f32x4 zero = {0.0f, 0.0f, 0.0f, 0.0f};
  f32x4 acc1[4][2], acc2[4][2];
#pragma unroll
  for (int i = 0; i < 4; ++i)
#pragma unroll
    for (int j = 0; j < 2; ++j) { acc1[i][j] = zero; acc2[i][j] = zero; }

  auto stage = [&](int s, int t) {
    gload16(aptr + t * 32, s_a + s * ABUF + tid * 8);
    gload16(b1p + (size_t)t * 512, s_b1 + s * BBUF + tid * 8);
  };
  auto loadB2 = [&](bf16x8 (&d)[2], int t) {
    d[0] = *(const bf16x8*)(p2_0 + (size_t)t * 512);
    d[1] = *(const bf16x8*)(p2_1 + (size_t)t * 512);
  };
  auto compute = [&](int s, const bf16x8 (&b2)[2]) {
    const unsigned short* pa = s_a + s * ABUF;
    const unsigned short* pb = s_b1 + s * BBUF;
    bf16x8 af[4], bf1[2];
#pragma unroll
    for (int m = 0; m < 4; ++m) af[m] = *(const bf16x8*)(pa + aoff[m]);
#pragma unroll
    for (int n = 0; n < 2; ++n) bf1[n] = *(const bf16x8*)(pb + b1off[n]);
    __builtin_amdgcn_s_setprio(1);
#pragma unroll
    for (int m = 0; m < 4; ++m)
#pragma unroll
      for (int n = 0; n < 2; ++n) {
        acc1[m][n] = __builtin_amdgcn_mfma_f32_16x16x32_bf16(af[m], bf1[n], acc1[m][n], 0, 0, 0);
        acc2[m][n] = __builtin_amdgcn_mfma_f32_16x16x32_bf16(af[m], b2[n], acc2[m][n], 0, 0, 0);
      }
    __builtin_amdgcn_s_setprio(0);
  };

  bf16x8 b2a[2], b2b[2], b2c[2];
  // prologue: tiles 0..2 (12 vmem in flight)
  stage(0, 0); loadB2(b2a, 0);
  stage(1, 1); loadB2(b2b, 1);
  stage(2, 2); loadB2(b2c, 2);

  // ITER: wait oldest tile's 4 ops (2 newer tiles = 8 outstanding), raw barrier
  // (memory clobber = compiler fence, no drain), compute, barrier, re-stage slot.
#define G1_ITER(S, B2, T, WAIT)                                               \
  asm volatile("s_waitcnt vmcnt(" #WAIT ")\n\ts_barrier" ::: "memory");       \
  compute(S, B2);                                                             \
  asm volatile("s_barrier" ::: "memory");                                     \
  if ((T) + 3 < NT) { stage(S, (T) + 3); loadB2(B2, (T) + 3); }

  for (int t = 0; t < NT - 2; t += 3) {   // t = 0,3,...,27 -> tiles 0..29
    G1_ITER(0, b2a, t, 8)
    G1_ITER(1, b2b, t + 1, 8)
    G1_ITER(2, b2c, t + 2, 8)
  }
  // tail: tile 30 (slot 0, staged at t=27), tile 31 (slot 1, staged at t=28)
  asm volatile("s_waitcnt vmcnt(4)\n\ts_barrier" ::: "memory");
  compute(0, b2a);
  asm volatile("s_waitcnt vmcnt(0)\n\ts_barrier" ::: "memory");
  compute(1, b2b);
#undef G1_ITER

  int hb = offs[e];
#pragma unroll
  for (int m = 0; m < 4; ++m) {
#pragma unroll
    for (int j = 0; j < 4; ++j) {
      int r = mt * 128 + wm + m * 16 + (lane >> 4) * 4 + j;
      if (r < ne) {
        size_t rowo = (size_t)(hb + r) * FFN;
#pragma unroll
        for (int n = 0; n < 2; ++n) {
          int col = nt * 128 + wn + n * 16 + rl;
          float c1 = acc1[m][n][j], c2 = acc2[m][n][j];
          float h = c1 / (1.0f + __expf(-c1)) * c2;
          hbuf[rowo + col] = f2bf(h);
        }
      }
    }
  }
}

// ========== GEMM2: A via LDS, B from packed global (reg dbuf) — round-9 verbatim ======
__global__ __launch_bounds__(512) void gemm2b_kernel(
    const unsigned short* __restrict__ hbuf, const unsigned short* __restrict__ pw2,
    const int* __restrict__ counts, const int* __restrict__ offs,
    const int* __restrict__ lists, const float* __restrict__ tok_w,
    float* __restrict__ ybuf) {
  constexpr int BUFSZ = 128 * 32;
  constexpr int NT = FFN / 32;
  int nt = blockIdx.x, mt = blockIdx.y, e = blockIdx.z;
  int ne = counts[e];
  if (mt * 128 >= ne) return;
  __shared__ unsigned short s_a[2 * BUFSZ];
  int tid = threadIdx.x;
  int hb = offs[e];
  int srow = tid >> 2, slot = tid & 3;
  int lchunk = slot ^ ((srow >> 1) & 3);
  int ar = mt * 128 + ((mt * 128 + srow < ne) ? srow : 0);
  const unsigned short* aptr = hbuf + (size_t)(hb + ar) * FFN + lchunk * 8;

  int lane = tid & 63, wv = tid >> 6;
  int wm = (wv >> 2) * 64, wn = (wv & 3) * 32;
  int rl = lane & 15, g = lane >> 4;
  int aoff[4];
#pragma unroll
  for (int m = 0; m < 4; ++m) aoff[m] = frag_off(wm + m * 16 + rl, g);

  size_t cb = (size_t)e * (HID / 16) + nt * 8 + (wv & 3) * 2;
  const unsigned short* p_0 = pw2 + (cb + 0) * (FFN / 32) * 512 + lane * 8;
  const unsigned short* p_1 = pw2 + (cb + 1) * (FFN / 32) * 512 + lane * 8;

  f32x4 zero = {0.0f, 0.0f, 0.0f, 0.0f};
  f32x4 acc[4][2];
#pragma unroll
  for (int i = 0; i < 4; ++i)
#pragma unroll
    for (int j = 0; j < 2; ++j) acc[i][j] = zero;

  auto stageA = [&](int s, int t) {
    gload16(aptr + t * 32, s_a + s * BUFSZ + tid * 8);
  };
  bf16x8 bX[2], bY[2];
  auto loadBX = [&](int t) {
    bX[0] = *(const bf16x8*)(p_0 + (size_t)t * 512);
    bX[1] = *(const bf16x8*)(p_1 + (size_t)t * 512);
  };
  auto loadBY = [&](int t) {
    bY[0] = *(const bf16x8*)(p_0 + (size_t)t * 512);
    bY[1] = *(const bf16x8*)(p_1 + (size_t)t * 512);
  };
  auto compute = [&](int s, bf16x8 (&b)[2]) {
    const unsigned short* pa = s_a + s * BUFSZ;
    bf16x8 af[4];
#pragma unroll
    for (int m = 0; m < 4; ++m) af[m] = *(const bf16x8*)(pa + aoff[m]);
#pragma unroll
    for (int m = 0; m < 4; ++m)
#pragma unroll
      for (int n = 0; n < 2; ++n)
        acc[m][n] = __builtin_amdgcn_mfma_f32_16x16x32_bf16(af[m], b[n], acc[m][n], 0, 0, 0);
  };

  stageA(0, 0);
  loadBX(0);
  __syncthreads();
  for (int t = 0; t < NT; t += 2) {
    stageA(1, t + 1);
    loadBY(t + 1);
    compute(0, bX);
    __syncthreads();
    if (t + 2 < NT) { stageA(0, t + 2); loadBX(t + 2); }
    compute(1, bY);
    __syncthreads();
  }

#pragma unroll
  for (int m = 0; m < 4; ++m) {
#pragma unroll
    for (int j = 0; j < 4; ++j) {
      int r = mt * 128 + wm + m * 16 + (lane >> 4) * 4 + j;
      if (r < ne) {
        int p = lists[e * T_TOKENS + r];
        float w = tok_w[p];
        float* yrow = ybuf + (size_t)p * HID;
#pragma unroll
        for (int n = 0; n < 2; ++n) {
          int col = nt * 128 + wn + n * 16 + rl;
          yrow[col] = acc[m][n][j] * w;
        }
      }
    }
  }
}

// ================= fallback path (ws too small): proven round-2 kernels ======

__global__ __launch_bounds__(512) void gemm1_kernel(
    const unsigned short* __restrict__ xbf,
    const float* __restrict__ w1, const float* __restrict__ v1,
    const int* __restrict__ counts, const int* __restrict__ offs,
    const int* __restrict__ lists, unsigned short* __restrict__ hbuf) {
  int nt = blockIdx.x, mt = blockIdx.y, e = blockIdx.z;
  int ne = counts[e];
  if (mt * 128 >= ne) return;
  int nrows = ne - mt * 128; if (nrows > 128) nrows = 128;
  __shared__ unsigned short s_a[128 * 40];
  __shared__ unsigned short s_b1[128 * 40];
  __shared__ unsigned short s_b2[128 * 40];
  const int* lst = lists + e * T_TOKENS + mt * 128;
  int tid = threadIdx.x;
  int sr = tid >> 2, sc = tid & 3;
  int pr = lst[(sr < nrows) ? sr : 0];
  const unsigned short* asrc = xbf + (size_t)(pr >> 1) * HID + sc * 8;
  size_t brow = ((size_t)e * FFN + nt * 128 + sr) * HID + sc * 8;
  const float* b1s = w1 + brow;
  const float* b2s = v1 + brow;
  int lane = tid & 63, wv = tid >> 6;
  int wm = (wv >> 2) * 64, wn = (wv & 3) * 32;
  int rl = lane & 15, kg = (lane >> 4) * 8;
  f32x4 zero = {0.0f, 0.0f, 0.0f, 0.0f};
  f32x4 acc1[4][2], acc2[4][2];
#pragma unroll
  for (int i = 0; i < 4; ++i)
#pragma unroll
    for (int j = 0; j < 2; ++j) { acc1[i][j] = zero; acc2[i][j] = zero; }
  int sdst = sr * 40 + sc * 8;
  for (int kk = 0; kk < HID; kk += 32) {
    uint4 av = *(const uint4*)(asrc + kk);
    float4 f0 = *(const float4*)(b1s + kk);
    float4 f1 = *(const float4*)(b1s + kk + 4);
    float4 g0 = *(const float4*)(b2s + kk);
    float4 g1 = *(const float4*)(b2s + kk + 4);
    *(uint4*)(s_a + sdst) = av;
    uint4 bv; bv.x = pack2(f0.x, f0.y); bv.y = pack2(f0.z, f0.w);
    bv.z = pack2(f1.x, f1.y); bv.w = pack2(f1.z, f1.w);
    *(uint4*)(s_b1 + sdst) = bv;
    uint4 cv; cv.x = pack2(g0.x, g0.y); cv.y = pack2(g0.z, g0.w);
    cv.z = pack2(g1.x, g1.y); cv.w = pack2(g1.z, g1.w);
    *(uint4*)(s_b2 + sdst) = cv;
    __syncthreads();
    bf16x8 af[4], bf1[2], bf2[2];
#pragma unroll
    for (int m = 0; m < 4; ++m)
      af[m] = *(const bf16x8*)(s_a + (wm + m * 16 + rl) * 40 + kg);
#pragma unroll
    for (int n = 0; n < 2; ++n) {
      bf1[n] = *(const bf16x8*)(s_b1 + (wn + n * 16 + rl) * 40 + kg);
      bf2[n] = *(const bf16x8*)(s_b2 + (wn + n * 16 + rl) * 40 + kg);
    }
#pragma unroll
    for (int m = 0; m < 4; ++m)
#pragma unroll
      for (int n = 0; n < 2; ++n) {
        acc1[m][n] = __builtin_amdgcn_mfma_f32_16x16x32_bf16(af[m], bf1[n], acc1[m][n], 0, 0, 0);
        acc2[m][n] = __builtin_amdgcn_mfma_f32_16x16x32_bf16(af[m], bf2[n], acc2[m][n], 0, 0, 0);
      }
    __syncthreads();
  }
  int hb = offs[e];
#pragma unroll
  for (int m = 0; m < 4; ++m) {
#pragma unroll
    for (int j = 0; j < 4; ++j) {
      int r = mt * 128 + wm + m * 16 + (lane >> 4) * 4 + j;
      if (r < ne) {
        size_t rowo = (size_t)(hb + r) * FFN;
#pragma unroll
        for (int n = 0; n < 2; ++n) {
          int col = nt * 128 + wn + n * 16 + rl;
          float c1 = acc1[m][n][j], c2 = acc2[m][n][j];
          float h = c1 / (1.0f + __expf(-c1)) * c2;
          hbuf[rowo + col] = f2bf(h);
        }
      }
    }
  }
}

__global__ __launch_bounds__(512) void gemm2_kernel(
    const unsigned short* __restrict__ hbuf, const float* __restrict__ w2,
    const int* __restrict__ counts, const int* __restrict__ offs,
    const int* __restrict__ lists, const float* __restrict__ tok_w,
    float* __restrict__ out) {
  int nt = blockIdx.x, mt = blockIdx.y, e = blockIdx.z;
  int ne = counts[e];
  if (mt * 128 >= ne) return;
  int nrows = ne - mt * 128; if (nrows > 128) nrows = 128;
  __shared__ unsigned short s_a[128 * 40];
  __shared__ unsigned short s_b[128 * 40];
  int tid = threadIdx.x;
  int hb = offs[e];
  int sr = tid >> 2, sc = tid & 3;
  int ar = mt * 128 + ((sr < nrows) ? sr : 0);
  const unsigned short* asrc = hbuf + (size_t)(hb + ar) * FFN + sc * 8;
  int bk = tid >> 4, bn = tid & 15;
  const float* bsrc = w2 + ((size_t)e * FFN + bk) * HID + nt * 128 + bn;
  int lane = tid & 63, wv = tid >> 6;
  int wm = (wv >> 2) * 64, wn = (wv & 3) * 32;
  int rl = lane & 15, kg = (lane >> 4) * 8;
  f32x4 zero = {0.0f, 0.0f, 0.0f, 0.0f};
  f32x4 acc[4][2];
#pragma unroll
  for (int i = 0; i < 4; ++i)
#pragma unroll
    for (int j = 0; j < 2; ++j) acc[i][j] = zero;
  int sdst = sr * 40 + sc * 8;
  for (int kk = 0; kk < FFN; kk += 32) {
    uint4 av = *(const uint4*)(asrc + kk);
    const float* bs = bsrc + (size_t)kk * HID;
    float bvals[8];
#pragma unroll
    for (int i = 0; i < 8; ++i) bvals[i] = bs[i * 16];
    *(uint4*)(s_a + sdst) = av;
#pragma unroll
    for (int i = 0; i < 8; ++i) s_b[(bn + i * 16) * 40 + bk] = f2bf(bvals[i]);
    __syncthreads();
    bf16x8 af[4], bfr[2];
#pragma unroll
    for (int m = 0; m < 4; ++m)
      af[m] = *(const bf16x8*)(s_a + (wm + m * 16 + rl) * 40 + kg);
#pragma unroll
    for (int n = 0; n < 2; ++n)
      bfr[n] = *(const bf16x8*)(s_b + (wn + n * 16 + rl) * 40 + kg);
#pragma unroll
    for (int m = 0; m < 4; ++m)
#pragma unroll
      for (int n = 0; n < 2; ++n)
        acc[m][n] = __builtin_amdgcn_mfma_f32_16x16x32_bf16(af[m], bfr[n], acc[m][n], 0, 0, 0);
    __syncthreads();
  }
#pragma unroll
  for (int m = 0; m < 4; ++m) {
#pragma unroll
    for (int j = 0; j < 4; ++j) {
      int r = mt * 128 + wm + m * 16 + (lane >> 4) * 4 + j;
      if (r < ne) {
        int p = lists[e * T_TOKENS + r];
        float w = tok_w[p];
        float* orow = out + (size_t)(p >> 1) * HID;
#pragma unroll
        for (int n = 0; n < 2; ++n) {
          int col = nt * 128 + wn + n * 16 + rl;
          atomicAdd(orow + col, acc[m][n][j] * w);
        }
      }
    }
  }
}

extern "C" void kernel_launch(void* const* d_in, const int* in_sizes, int n_in,
                              void* d_out, int out_size, void* d_ws, size_t ws_size,
                              hipStream_t stream) {
  const float* x  = (const float*)d_in[0];
  const float* rw = (const float*)d_in[1];
  const float* w1 = (const float*)d_in[2];
  const float* v1 = (const float*)d_in[3];
  const float* w2 = (const float*)d_in[4];
  float* out = (float*)d_out;
  char* ws = (char*)d_ws;
  if (ws_size < META_END) return;

  unsigned short* xbf  = (unsigned short*)(ws + XBF_OFF);
  unsigned short* hbuf = (unsigned short*)(ws + HBUF_OFF);
  int*   tok_e  = (int*)(ws + TOKE_OFF);
  float* tok_w  = (float*)(ws + TOKW_OFF);
  int*   counts = (int*)(ws + CNT_OFF);
  int*   offs   = (int*)(ws + OFF_OFF);
  int*   lists  = (int*)(ws + LIST_OFF);

  router_kernel<<<T_TOKENS / 4, 256, 0, stream>>>(x, rw, tok_e, tok_w, xbf);
  scatter_offsets_kernel<<<1, 1024, 0, stream>>>(tok_e, counts, offs, lists);

  if (ws_size >= WS_BIG) {
    unsigned short* pb1 = (unsigned short*)(ws + PB1_OFF);
    unsigned short* pb2 = (unsigned short*)(ws + PB2_OFF);
    unsigned short* pw2 = (unsigned short*)(ws + PW2_OFF);
    float* ybuf = (float*)(ws + YBUF_OFF);   // overlaps pb1: dead after gemm1b
    pack_w1v1_kernel<<<dim3(FFN / 16, HID / 128, 2 * NE), 256, 0, stream>>>(w1, v1, pb1, pb2);
    pack_w2_kernel<<<dim3(HID / 64, FFN / 64, NE), 256, 0, stream>>>(w2, pw2);
    gemm1b_kernel<<<dim3(FFN / 128, T_TOKENS / 128, NE), 512, 0, stream>>>(
        xbf, pb1, pb2, counts, offs, lists, hbuf);
    gemm2b_kernel<<<dim3(HID / 128, T_TOKENS / 128, NE), 512, 0, stream>>>(
        hbuf, pw2, counts, offs, lists, tok_w, ybuf);
    combine_kernel<<<T_TOKENS, 256, 0, stream>>>(ybuf, out);
  } else {
    hipMemsetAsync(d_out, 0, (size_t)T_TOKENS * HID * 4, stream);
    gemm1_kernel<<<dim3(FFN / 128, T_TOKENS / 128, NE), 512, 0, stream>>>(
        xbf, w1, v1, counts, offs, lists, hbuf);
    gemm2_kernel<<<dim3(HID / 128, T_TOKENS / 128, NE), 512, 0, stream>>>(
        hbuf, w2, counts, offs, lists, tok_w, out);
  }
}

// Round 11
// 244.995 us; speedup vs baseline: 1.1441x; 1.1441x over previous
//
#include <hip/hip_runtime.h>
#include <stdint.h>

#define T_TOKENS 4096
#define HID 1024
#define FFN 2048
#define NE 8

typedef __attribute__((ext_vector_type(8))) short bf16x8;
typedef __attribute__((ext_vector_type(4))) float f32x4;

__device__ __forceinline__ unsigned short f2bf(float f) {
  union { float f; uint32_t u; } v; v.f = f;
  uint32_t r = v.u + 0x7FFFu + ((v.u >> 16) & 1u);
  return (unsigned short)(r >> 16);
}

__device__ __forceinline__ uint32_t pack2(float a, float b) {
  return (uint32_t)f2bf(a) | ((uint32_t)f2bf(b) << 16);
}

__device__ __forceinline__ float bf2f(uint32_t lo16) {
  union { uint32_t u; float f; } v; v.u = lo16 << 16; return v.f;
}

__device__ __forceinline__ void gload16(const unsigned short* g, unsigned short* l) {
  __builtin_amdgcn_global_load_lds(
      (const __attribute__((address_space(1))) void*)(g),
      (__attribute__((address_space(3))) void*)(l), 16, 0, 0);
}

// XOR chunk swizzle for the gathered A tile [128 rows][32 k] bf16.
__device__ __forceinline__ int frag_off(int r, int g) {
  return r * 32 + ((g ^ ((r >> 1) & 3)) << 3);
}

// ---- ws layout ----
constexpr size_t XBF_OFF  = 0;                                       // 8 MB
constexpr size_t HBUF_OFF = (size_t)T_TOKENS * HID * 2;              // 32 MB
constexpr size_t TOKE_OFF = HBUF_OFF + (size_t)T_TOKENS * 2 * FFN * 2;
constexpr size_t TOKW_OFF = TOKE_OFF + (size_t)T_TOKENS * 2 * 4;
constexpr size_t CNT_OFF  = TOKW_OFF + (size_t)T_TOKENS * 2 * 4;
constexpr size_t OFF_OFF  = CNT_OFF + 64;
constexpr size_t LIST_OFF = OFF_OFF + 64;
constexpr size_t META_END = LIST_OFF + (size_t)NE * T_TOKENS * 4;    // ~40.2 MB
constexpr size_t PB1_OFF  = META_END;                                // 32 MB (ybuf reuses)
constexpr size_t PB2_OFF  = PB1_OFF + (size_t)NE * FFN * HID * 2;    // 32 MB
constexpr size_t PW2_OFF  = PB2_OFF + (size_t)NE * FFN * HID * 2;    // 32 MB
constexpr size_t WS_BIG   = PW2_OFF + (size_t)NE * HID * FFN * 2;    // ~136.2 MB
constexpr size_t YBUF_OFF = PB1_OFF;   // ybuf [8192][HID] bf16 = 16 MB; pb1 dead after gemm1b

// ---- pack w1/v1 into fragment-linear layout: [e][col/16][k/32][512] (validated r8/r9) ----
__global__ __launch_bounds__(256) void pack_w1v1_kernel(const float* __restrict__ w1,
                                                        const float* __restrict__ v1,
                                                        unsigned short* __restrict__ pb1,
                                                        unsigned short* __restrict__ pb2) {
  int colblk = blockIdx.x;            // 0..127 (FFN/16)
  int kslab  = blockIdx.y;            // 0..7   (HID/128)
  int ez     = blockIdx.z;            // 0..15
  const float* src = (ez < NE) ? w1 : v1;
  unsigned short* dst = (ez < NE) ? pb1 : pb2;
  int e = ez & (NE - 1);
  __shared__ unsigned short lds[2048];
  int t = threadIdx.x;
  int c  = colblk * 16 + (t >> 4);
  int k0 = kslab * 128 + (t & 15) * 8;
  const float* sp = src + ((size_t)e * FFN + c) * HID + k0;
  float4 a = *(const float4*)sp;
  float4 b = *(const float4*)(sp + 4);
  uint4 o;
  o.x = pack2(a.x, a.y); o.y = pack2(a.z, a.w);
  o.z = pack2(b.x, b.y); o.w = pack2(b.z, b.w);
  int chunk = ((t & 15) >> 2) * 64 + ((t & 3) * 16 + (t >> 4));
  int pos = chunk ^ ((chunk >> 4) & 15);
  *(uint4*)(lds + pos * 8) = o;
  __syncthreads();
  int rpos = t ^ ((t >> 4) & 15);
  uint4 v = *(const uint4*)(lds + rpos * 8);
  unsigned short* dp = dst + (((size_t)e * (FFN / 16) + colblk) * (HID / 32) + kslab * 4) * 512 + t * 8;
  *(uint4*)dp = v;
}

// ---- pack w2 [e][k(FFN)][c(HID)] f32 -> [e][c/16][k/32][512] bf16 (validated r8/r9) ----
__global__ __launch_bounds__(256) void pack_w2_kernel(const float* __restrict__ w2,
                                                      unsigned short* __restrict__ pw2) {
  int cb = blockIdx.x;   // 0..15
  int kb = blockIdx.y;   // 0..31
  int e  = blockIdx.z;
  __shared__ unsigned short s[64][68];
  int t = threadIdx.x;
  int tr = t >> 4, tc = (t & 15) * 4;
  const float* src = w2 + ((size_t)e * FFN + kb * 64) * HID + cb * 64;
#pragma unroll
  for (int i = 0; i < 4; ++i) {
    int k = tr + i * 16;
    float4 v = *(const float4*)(src + (size_t)k * HID + tc);
    s[k][tc + 0] = f2bf(v.x); s[k][tc + 1] = f2bf(v.y);
    s[k][tc + 2] = f2bf(v.z); s[k][tc + 3] = f2bf(v.w);
  }
  __syncthreads();
#pragma unroll
  for (int half = 0; half < 2; ++half) {
    int cid = t + half * 256;
    int colblk_l = cid >> 7;
    int ks_l = (cid >> 6) & 1;
    int lane = cid & 63;
    unsigned short tmp[8];
#pragma unroll
    for (int j = 0; j < 8; ++j)
      tmp[j] = s[ks_l * 32 + (lane >> 4) * 8 + j][colblk_l * 16 + (lane & 15)];
    uint4 o;
    o.x = tmp[0] | (tmp[1] << 16); o.y = tmp[2] | (tmp[3] << 16);
    o.z = tmp[4] | (tmp[5] << 16); o.w = tmp[6] | (tmp[7] << 16);
    unsigned short* dp = pw2 + (((size_t)e * (HID / 16) + cb * 4 + colblk_l) * (FFN / 32)
                                + kb * 2 + ks_l) * 512 + lane * 8;
    *(uint4*)dp = o;
  }
}

// ---- router (+ fused x->bf16 cast), vectorized: float4 x, b128 LDS, uint2 stores ----
__global__ __launch_bounds__(256) void router_kernel(const float* __restrict__ x,
                                                     const float* __restrict__ rw,
                                                     int* __restrict__ tok_e,
                                                     float* __restrict__ tok_w,
                                                     unsigned short* __restrict__ xbf) {
  __shared__ float s_rw[NE * HID];
  int tid = threadIdx.x;
  for (int i = tid; i < NE * HID / 4; i += 256)
    ((float4*)s_rw)[i] = ((const float4*)rw)[i];
  __syncthreads();
  int wave = tid >> 6, lane = tid & 63;
  int t = blockIdx.x * 4 + wave;
  const float* xr = x + (size_t)t * HID;
  unsigned short* xbr = xbf + (size_t)t * HID;
  float acc[NE];
#pragma unroll
  for (int e = 0; e < NE; ++e) acc[e] = 0.0f;
#pragma unroll
  for (int c = 0; c < HID / 256; ++c) {     // 4 iters, 4 elems/lane each
    int idx = c * 256 + lane * 4;
    float4 xv = *(const float4*)(xr + idx);
    uint2 pk; pk.x = pack2(xv.x, xv.y); pk.y = pack2(xv.z, xv.w);
    *(uint2*)(xbr + idx) = pk;              // fused bf16 cast
#pragma unroll
    for (int e = 0; e < NE; ++e) {
      float4 rv = *(const float4*)(s_rw + e * HID + idx);
      acc[e] += xv.x * rv.x + xv.y * rv.y + xv.z * rv.z + xv.w * rv.w;
    }
  }
#pragma unroll
  for (int e = 0; e < NE; ++e)
    for (int off = 32; off > 0; off >>= 1) acc[e] += __shfl_down(acc[e], off);
  if (lane == 0) {
    float m = acc[0];
#pragma unroll
    for (int e = 1; e < NE; ++e) m = fmaxf(m, acc[e]);
    float p[NE], Z = 0.0f;
#pragma unroll
    for (int e = 0; e < NE; ++e) { p[e] = expf(acc[e] - m); Z += p[e]; }
    int e0 = 0;
#pragma unroll
    for (int e = 1; e < NE; ++e) if (p[e] > p[e0]) e0 = e;
    int e1 = (e0 == 0) ? 1 : 0;
#pragma unroll
    for (int e = 0; e < NE; ++e) if (e != e0 && p[e] > p[e1]) e1 = e;
    float w0 = p[e0] / Z, w1 = p[e1] / Z;
    float nrm = w0 + w1;  // P_NORM = 1
    tok_e[t * 2] = e0; tok_e[t * 2 + 1] = e1;
    tok_w[t * 2] = w0 / nrm; tok_w[t * 2 + 1] = w1 / nrm;
  }
}

// ---- merged scatter + offsets (single block; LDS counters) ----
__global__ __launch_bounds__(1024) void scatter_offsets_kernel(
    const int* __restrict__ tok_e, int* __restrict__ counts,
    int* __restrict__ offs, int* __restrict__ lists) {
  __shared__ int c[NE];
  int tid = threadIdx.x;
  if (tid < NE) c[tid] = 0;
  __syncthreads();
  for (int p = tid; p < T_TOKENS * 2; p += 1024) {
    int e = tok_e[p];
    int pos = atomicAdd(&c[e], 1);
    lists[e * T_TOKENS + pos] = p;
  }
  __syncthreads();
  if (tid == 0) {
    int r = 0;
    for (int e = 0; e < NE; ++e) { counts[e] = c[e]; offs[e] = r; r += c[e]; }
  }
}

// ---- combine: out[t] = y[2t] + y[2t+1], ybuf is bf16 ----
__global__ __launch_bounds__(256) void combine_kernel(const unsigned short* __restrict__ ybuf,
                                                      float* __restrict__ out) {
  int t = blockIdx.x;
  int c = threadIdx.x;          // 4 elems / thread
  uint2 ua = *(const uint2*)(ybuf + (size_t)(2 * t) * HID + c * 4);
  uint2 ub = *(const uint2*)(ybuf + (size_t)(2 * t + 1) * HID + c * 4);
  float4 r;
  r.x = bf2f(ua.x & 0xffff) + bf2f(ub.x & 0xffff);
  r.y = bf2f(ua.x >> 16)    + bf2f(ub.x >> 16);
  r.z = bf2f(ua.y & 0xffff) + bf2f(ub.y & 0xffff);
  r.w = bf2f(ua.y >> 16)    + bf2f(ub.y >> 16);
  ((float4*)(out + (size_t)t * HID))[c] = r;
}

// ========== GEMM1 (round-9 exact): A swizzled-LDS, B1 packed->LDS, B2 packed->regs ====
// 512 thr = 8 waves (2Mx4N, 64x32/wave), block 128x128, 2-phase dbuf. LDS 32 KB.
__global__ __launch_bounds__(512) void gemm1b_kernel(
    const unsigned short* __restrict__ xbf,
    const unsigned short* __restrict__ pb1, const unsigned short* __restrict__ pb2,
    const int* __restrict__ counts, const int* __restrict__ offs,
    const int* __restrict__ lists, unsigned short* __restrict__ hbuf) {
  constexpr int ABUF = 128 * 32;   // 8 KB
  constexpr int BBUF = 128 * 32;   // 8 KB
  constexpr int NT = HID / 32;     // 32 (even)
  int nt = blockIdx.x, mt = blockIdx.y, e = blockIdx.z;
  int ne = counts[e];
  if (mt * 128 >= ne) return;
  __shared__ unsigned short s_a[2 * ABUF];
  __shared__ unsigned short s_b1[2 * BBUF];
  int tid = threadIdx.x;
  int srow = tid >> 2, slot = tid & 3;
  int lchunk = slot ^ ((srow >> 1) & 3);
  const int* lst = lists + e * T_TOKENS + mt * 128;
  int tok = lst[(mt * 128 + srow < ne) ? srow : 0] >> 1;
  const unsigned short* aptr = xbf + (size_t)tok * HID + lchunk * 8;
  int g8 = tid >> 6, ln = tid & 63;
  const unsigned short* b1p =
      pb1 + ((size_t)(e * (FFN / 16) + nt * 8 + g8) * (HID / 32)) * 512 + ln * 8;

  int lane = tid & 63, wv = tid >> 6;
  int wm = (wv >> 2) * 64, wn = (wv & 3) * 32;
  int rl = lane & 15, g = lane >> 4;
  int aoff[4];
#pragma unroll
  for (int m = 0; m < 4; ++m) aoff[m] = frag_off(wm + m * 16 + rl, g);
  int b1off[2];
#pragma unroll
  for (int n = 0; n < 2; ++n) b1off[n] = (((wv & 3) * 2 + n) * 64 + lane) * 8;
  size_t cb2 = (size_t)e * (FFN / 16) + nt * 8 + (wv & 3) * 2;
  const unsigned short* p2_0 = pb2 + (cb2 + 0) * (HID / 32) * 512 + lane * 8;
  const unsigned short* p2_1 = pb2 + (cb2 + 1) * (HID / 32) * 512 + lane * 8;

  f32x4 zero = {0.0f, 0.0f, 0.0f, 0.0f};
  f32x4 acc1[4][2], acc2[4][2];
#pragma unroll
  for (int i = 0; i < 4; ++i)
#pragma unroll
    for (int j = 0; j < 2; ++j) { acc1[i][j] = zero; acc2[i][j] = zero; }

  auto stage = [&](int s, int t) {   // s literal -> const-folded
    gload16(aptr + t * 32, s_a + s * ABUF + tid * 8);
    gload16(b1p + (size_t)t * 512, s_b1 + s * BBUF + tid * 8);
  };
  bf16x8 b2X[2], b2Y[2];
  auto loadBX = [&](int t) {
    b2X[0] = *(const bf16x8*)(p2_0 + (size_t)t * 512);
    b2X[1] = *(const bf16x8*)(p2_1 + (size_t)t * 512);
  };
  auto loadBY = [&](int t) {
    b2Y[0] = *(const bf16x8*)(p2_0 + (size_t)t * 512);
    b2Y[1] = *(const bf16x8*)(p2_1 + (size_t)t * 512);
  };
  auto compute = [&](int s, bf16x8 (&b2)[2]) {
    const unsigned short* pa = s_a + s * ABUF;
    const unsigned short* pb = s_b1 + s * BBUF;
    bf16x8 af[4], bf1[2];
#pragma unroll
    for (int m = 0; m < 4; ++m) af[m] = *(const bf16x8*)(pa + aoff[m]);
#pragma unroll
    for (int n = 0; n < 2; ++n) bf1[n] = *(const bf16x8*)(pb + b1off[n]);
#pragma unroll
    for (int m = 0; m < 4; ++m)
#pragma unroll
      for (int n = 0; n < 2; ++n) {
        acc1[m][n] = __builtin_amdgcn_mfma_f32_16x16x32_bf16(af[m], bf1[n], acc1[m][n], 0, 0, 0);
        acc2[m][n] = __builtin_amdgcn_mfma_f32_16x16x32_bf16(af[m], b2[n], acc2[m][n], 0, 0, 0);
      }
  };

  stage(0, 0);
  loadBX(0);
  __syncthreads();
  for (int t = 0; t < NT; t += 2) {
    stage(1, t + 1);
    loadBY(t + 1);
    compute(0, b2X);
    __syncthreads();
    if (t + 2 < NT) { stage(0, t + 2); loadBX(t + 2); }
    compute(1, b2Y);
    __syncthreads();
  }

  int hb = offs[e];
#pragma unroll
  for (int m = 0; m < 4; ++m) {
#pragma unroll
    for (int j = 0; j < 4; ++j) {
      int r = mt * 128 + wm + m * 16 + (lane >> 4) * 4 + j;
      if (r < ne) {
        size_t rowo = (size_t)(hb + r) * FFN;
#pragma unroll
        for (int n = 0; n < 2; ++n) {
          int col = nt * 128 + wn + n * 16 + rl;
          float c1 = acc1[m][n][j], c2 = acc2[m][n][j];
          float h = c1 / (1.0f + __expf(-c1)) * c2;
          hbuf[rowo + col] = f2bf(h);
        }
      }
    }
  }
}

// ========== GEMM2: A via LDS, B from packed global (reg dbuf); bf16 ybuf stores ======
__global__ __launch_bounds__(512) void gemm2b_kernel(
    const unsigned short* __restrict__ hbuf, const unsigned short* __restrict__ pw2,
    const int* __restrict__ counts, const int* __restrict__ offs,
    const int* __restrict__ lists, const float* __restrict__ tok_w,
    unsigned short* __restrict__ ybuf) {
  constexpr int BUFSZ = 128 * 32;
  constexpr int NT = FFN / 32;
  int nt = blockIdx.x, mt = blockIdx.y, e = blockIdx.z;
  int ne = counts[e];
  if (mt * 128 >= ne) return;
  __shared__ unsigned short s_a[2 * BUFSZ];
  int tid = threadIdx.x;
  int hb = offs[e];
  int srow = tid >> 2, slot = tid & 3;
  int lchunk = slot ^ ((srow >> 1) & 3);
  int ar = mt * 128 + ((mt * 128 + srow < ne) ? srow : 0);
  const unsigned short* aptr = hbuf + (size_t)(hb + ar) * FFN + lchunk * 8;

  int lane = tid & 63, wv = tid >> 6;
  int wm = (wv >> 2) * 64, wn = (wv & 3) * 32;
  int rl = lane & 15, g = lane >> 4;
  int aoff[4];
#pragma unroll
  for (int m = 0; m < 4; ++m) aoff[m] = frag_off(wm + m * 16 + rl, g);

  size_t cb = (size_t)e * (HID / 16) + nt * 8 + (wv & 3) * 2;
  const unsigned short* p_0 = pw2 + (cb + 0) * (FFN / 32) * 512 + lane * 8;
  const unsigned short* p_1 = pw2 + (cb + 1) * (FFN / 32) * 512 + lane * 8;

  f32x4 zero = {0.0f, 0.0f, 0.0f, 0.0f};
  f32x4 acc[4][2];
#pragma unroll
  for (int i = 0; i < 4; ++i)
#pragma unroll
    for (int j = 0; j < 2; ++j) acc[i][j] = zero;

  auto stageA = [&](int s, int t) {
    gload16(aptr + t * 32, s_a + s * BUFSZ + tid * 8);
  };
  bf16x8 bX[2], bY[2];
  auto loadBX = [&](int t) {
    bX[0] = *(const bf16x8*)(p_0 + (size_t)t * 512);
    bX[1] = *(const bf16x8*)(p_1 + (size_t)t * 512);
  };
  auto loadBY = [&](int t) {
    bY[0] = *(const bf16x8*)(p_0 + (size_t)t * 512);
    bY[1] = *(const bf16x8*)(p_1 + (size_t)t * 512);
  };
  auto compute = [&](int s, bf16x8 (&b)[2]) {
    const unsigned short* pa = s_a + s * BUFSZ;
    bf16x8 af[4];
#pragma unroll
    for (int m = 0; m < 4; ++m) af[m] = *(const bf16x8*)(pa + aoff[m]);
#pragma unroll
    for (int m = 0; m < 4; ++m)
#pragma unroll
      for (int n = 0; n < 2; ++n)
        acc[m][n] = __builtin_amdgcn_mfma_f32_16x16x32_bf16(af[m], b[n], acc[m][n], 0, 0, 0);
  };

  stageA(0, 0);
  loadBX(0);
  __syncthreads();
  for (int t = 0; t < NT; t += 2) {
    stageA(1, t + 1);
    loadBY(t + 1);
    compute(0, bX);
    __syncthreads();
    if (t + 2 < NT) { stageA(0, t + 2); loadBX(t + 2); }
    compute(1, bY);
    __syncthreads();
  }

#pragma unroll
  for (int m = 0; m < 4; ++m) {
#pragma unroll
    for (int j = 0; j < 4; ++j) {
      int r = mt * 128 + wm + m * 16 + (lane >> 4) * 4 + j;
      if (r < ne) {
        int p = lists[e * T_TOKENS + r];
        float w = tok_w[p];
        unsigned short* yrow = ybuf + (size_t)p * HID;   // pair row, written once
#pragma unroll
        for (int n = 0; n < 2; ++n) {
          int col = nt * 128 + wn + n * 16 + rl;
          yrow[col] = f2bf(acc[m][n][j] * w);
        }
      }
    }
  }
}

// ================= fallback path (ws too small): proven round-2 kernels ======

__global__ __launch_bounds__(512) void gemm1_kernel(
    const unsigned short* __restrict__ xbf,
    const float* __restrict__ w1, const float* __restrict__ v1,
    const int* __restrict__ counts, const int* __restrict__ offs,
    const int* __restrict__ lists, unsigned short* __restrict__ hbuf) {
  int nt = blockIdx.x, mt = blockIdx.y, e = blockIdx.z;
  int ne = counts[e];
  if (mt * 128 >= ne) return;
  int nrows = ne - mt * 128; if (nrows > 128) nrows = 128;
  __shared__ unsigned short s_a[128 * 40];
  __shared__ unsigned short s_b1[128 * 40];
  __shared__ unsigned short s_b2[128 * 40];
  const int* lst = lists + e * T_TOKENS + mt * 128;
  int tid = threadIdx.x;
  int sr = tid >> 2, sc = tid & 3;
  int pr = lst[(sr < nrows) ? sr : 0];
  const unsigned short* asrc = xbf + (size_t)(pr >> 1) * HID + sc * 8;
  size_t brow = ((size_t)e * FFN + nt * 128 + sr) * HID + sc * 8;
  const float* b1s = w1 + brow;
  const float* b2s = v1 + brow;
  int lane = tid & 63, wv = tid >> 6;
  int wm = (wv >> 2) * 64, wn = (wv & 3) * 32;
  int rl = lane & 15, kg = (lane >> 4) * 8;
  f32x4 zero = {0.0f, 0.0f, 0.0f, 0.0f};
  f32x4 acc1[4][2], acc2[4][2];
#pragma unroll
  for (int i = 0; i < 4; ++i)
#pragma unroll
    for (int j = 0; j < 2; ++j) { acc1[i][j] = zero; acc2[i][j] = zero; }
  int sdst = sr * 40 + sc * 8;
  for (int kk = 0; kk < HID; kk += 32) {
    uint4 av = *(const uint4*)(asrc + kk);
    float4 f0 = *(const float4*)(b1s + kk);
    float4 f1 = *(const float4*)(b1s + kk + 4);
    float4 g0 = *(const float4*)(b2s + kk);
    float4 g1 = *(const float4*)(b2s + kk + 4);
    *(uint4*)(s_a + sdst) = av;
    uint4 bv; bv.x = pack2(f0.x, f0.y); bv.y = pack2(f0.z, f0.w);
    bv.z = pack2(f1.x, f1.y); bv.w = pack2(f1.z, f1.w);
    *(uint4*)(s_b1 + sdst) = bv;
    uint4 cv; cv.x = pack2(g0.x, g0.y); cv.y = pack2(g0.z, g0.w);
    cv.z = pack2(g1.x, g1.y); cv.w = pack2(g1.z, g1.w);
    *(uint4*)(s_b2 + sdst) = cv;
    __syncthreads();
    bf16x8 af[4], bf1[2], bf2[2];
#pragma unroll
    for (int m = 0; m < 4; ++m)
      af[m] = *(const bf16x8*)(s_a + (wm + m * 16 + rl) * 40 + kg);
#pragma unroll
    for (int n = 0; n < 2; ++n) {
      bf1[n] = *(const bf16x8*)(s_b1 + (wn + n * 16 + rl) * 40 + kg);
      bf2[n] = *(const bf16x8*)(s_b2 + (wn + n * 16 + rl) * 40 + kg);
    }
#pragma unroll
    for (int m = 0; m < 4; ++m)
#pragma unroll
      for (int n = 0; n < 2; ++n) {
        acc1[m][n] = __builtin_amdgcn_mfma_f32_16x16x32_bf16(af[m], bf1[n], acc1[m][n], 0, 0, 0);
        acc2[m][n] = __builtin_amdgcn_mfma_f32_16x16x32_bf16(af[m], bf2[n], acc2[m][n], 0, 0, 0);
      }
    __syncthreads();
  }
  int hb = offs[e];
#pragma unroll
  for (int m = 0; m < 4; ++m) {
#pragma unroll
    for (int j = 0; j < 4; ++j) {
      int r = mt * 128 + wm + m * 16 + (lane >> 4) * 4 + j;
      if (r < ne) {
        size_t rowo = (size_t)(hb + r) * FFN;
#pragma unroll
        for (int n = 0; n < 2; ++n) {
          int col = nt * 128 + wn + n * 16 + rl;
          float c1 = acc1[m][n][j], c2 = acc2[m][n][j];
          float h = c1 / (1.0f + __expf(-c1)) * c2;
          hbuf[rowo + col] = f2bf(h);
        }
      }
    }
  }
}

__global__ __launch_bounds__(512) void gemm2_kernel(
    const unsigned short* __restrict__ hbuf, const float* __restrict__ w2,
    const int* __restrict__ counts, const int* __restrict__ offs,
    const int* __restrict__ lists, const float* __restrict__ tok_w,
    float* __restrict__ out) {
  int nt = blockIdx.x, mt = blockIdx.y, e = blockIdx.z;
  int ne = counts[e];
  if (mt * 128 >= ne) return;
  int nrows = ne - mt * 128; if (nrows > 128) nrows = 128;
  __shared__ unsigned short s_a[128 * 40];
  __shared__ unsigned short s_b[128 * 40];
  int tid = threadIdx.x;
  int hb = offs[e];
  int sr = tid >> 2, sc = tid & 3;
  int ar = mt * 128 + ((sr < nrows) ? sr : 0);
  const unsigned short* asrc = hbuf + (size_t)(hb + ar) * FFN + sc * 8;
  int bk = tid >> 4, bn = tid & 15;
  const float* bsrc = w2 + ((size_t)e * FFN + bk) * HID + nt * 128 + bn;
  int lane = tid & 63, wv = tid >> 6;
  int wm = (wv >> 2) * 64, wn = (wv & 3) * 32;
  int rl = lane & 15, kg = (lane >> 4) * 8;
  f32x4 zero = {0.0f, 0.0f, 0.0f, 0.0f};
  f32x4 acc[4][2];
#pragma unroll
  for (int i = 0; i < 4; ++i)
#pragma unroll
    for (int j = 0; j < 2; ++j) acc[i][j] = zero;
  int sdst = sr * 40 + sc * 8;
  for (int kk = 0; kk < FFN; kk += 32) {
    uint4 av = *(const uint4*)(asrc + kk);
    const float* bs = bsrc + (size_t)kk * HID;
    float bvals[8];
#pragma unroll
    for (int i = 0; i < 8; ++i) bvals[i] = bs[i * 16];
    *(uint4*)(s_a + sdst) = av;
#pragma unroll
    for (int i = 0; i < 8; ++i) s_b[(bn + i * 16) * 40 + bk] = f2bf(bvals[i]);
    __syncthreads();
    bf16x8 af[4], bfr[2];
#pragma unroll
    for (int m = 0; m < 4; ++m)
      af[m] = *(const bf16x8*)(s_a + (wm + m * 16 + rl) * 40 + kg);
#pragma unroll
    for (int n = 0; n < 2; ++n)
      bfr[n] = *(const bf16x8*)(s_b + (wn + n * 16 + rl) * 40 + kg);
#pragma unroll
    for (int m = 0; m < 4; ++m)
#pragma unroll
      for (int n = 0; n < 2; ++n)
        acc[m][n] = __builtin_amdgcn_mfma_f32_16x16x32_bf16(af[m], bfr[n], acc[m][n], 0, 0, 0);
    __syncthreads();
  }
#pragma unroll
  for (int m = 0; m < 4; ++m) {
#pragma unroll
    for (int j = 0; j < 4; ++j) {
      int r = mt * 128 + wm + m * 16 + (lane >> 4) * 4 + j;
      if (r < ne) {
        int p = lists[e * T_TOKENS + r];
        float w = tok_w[p];
        float* orow = out + (size_t)(p >> 1) * HID;
#pragma unroll
        for (int n = 0; n < 2; ++n) {
          int col = nt * 128 + wn + n * 16 + rl;
          atomicAdd(orow + col, acc[m][n][j] * w);
        }
      }
    }
  }
}

extern "C" void kernel_launch(void* const* d_in, const int* in_sizes, int n_in,
                              void* d_out, int out_size, void* d_ws, size_t ws_size,
                              hipStream_t stream) {
  const float* x  = (const float*)d_in[0];
  const float* rw = (const float*)d_in[1];
  const float* w1 = (const float*)d_in[2];
  const float* v1 = (const float*)d_in[3];
  const float* w2 = (const float*)d_in[4];
  float* out = (float*)d_out;
  char* ws = (char*)d_ws;
  if (ws_size < META_END) return;

  unsigned short* xbf  = (unsigned short*)(ws + XBF_OFF);
  unsigned short* hbuf = (unsigned short*)(ws + HBUF_OFF);
  int*   tok_e  = (int*)(ws + TOKE_OFF);
  float* tok_w  = (float*)(ws + TOKW_OFF);
  int*   counts = (int*)(ws + CNT_OFF);
  int*   offs   = (int*)(ws + OFF_OFF);
  int*   lists  = (int*)(ws + LIST_OFF);

  router_kernel<<<T_TOKENS / 4, 256, 0, stream>>>(x, rw, tok_e, tok_w, xbf);
  scatter_offsets_kernel<<<1, 1024, 0, stream>>>(tok_e, counts, offs, lists);

  if (ws_size >= WS_BIG) {
    unsigned short* pb1 = (unsigned short*)(ws + PB1_OFF);
    unsigned short* pb2 = (unsigned short*)(ws + PB2_OFF);
    unsigned short* pw2 = (unsigned short*)(ws + PW2_OFF);
    unsigned short* ybuf = (unsigned short*)(ws + YBUF_OFF);  // overlaps pb1 (dead after gemm1b)
    pack_w1v1_kernel<<<dim3(FFN / 16, HID / 128, 2 * NE), 256, 0, stream>>>(w1, v1, pb1, pb2);
    pack_w2_kernel<<<dim3(HID / 64, FFN / 64, NE), 256, 0, stream>>>(w2, pw2);
    gemm1b_kernel<<<dim3(FFN / 128, T_TOKENS / 128, NE), 512, 0, stream>>>(
        xbf, pb1, pb2, counts, offs, lists, hbuf);
    gemm2b_kernel<<<dim3(HID / 128, T_TOKENS / 128, NE), 512, 0, stream>>>(
        hbuf, pw2, counts, offs, lists, tok_w, ybuf);
    combine_kernel<<<T_TOKENS, 256, 0, stream>>>(ybuf, out);
  } else {
    hipMemsetAsync(d_out, 0, (size_t)T_TOKENS * HID * 4, stream);
    gemm1_kernel<<<dim3(FFN / 128, T_TOKENS / 128, NE), 512, 0, stream>>>(
        xbf, w1, v1, counts, offs, lists, hbuf);
    gemm2_kernel<<<dim3(HID / 128, T_TOKENS / 128, NE), 512, 0, stream>>>(
        hbuf, w2, counts, offs, lists, tok_w, out);
  }
}

// Round 12
// 229.617 us; speedup vs baseline: 1.2207x; 1.0670x over previous
//
#include <hip/hip_runtime.h>
#include <stdint.h>

#define T_TOKENS 4096
#define HID 1024
#define FFN 2048
#define NE 8

typedef __attribute__((ext_vector_type(8))) short bf16x8;
typedef __attribute__((ext_vector_type(4))) float f32x4;

__device__ __forceinline__ unsigned short f2bf(float f) {
  union { float f; uint32_t u; } v; v.f = f;
  uint32_t r = v.u + 0x7FFFu + ((v.u >> 16) & 1u);
  return (unsigned short)(r >> 16);
}

__device__ __forceinline__ uint32_t pack2(float a, float b) {
  return (uint32_t)f2bf(a) | ((uint32_t)f2bf(b) << 16);
}

__device__ __forceinline__ float bf2f(uint32_t lo16) {
  union { uint32_t u; float f; } v; v.u = lo16 << 16; return v.f;
}

__device__ __forceinline__ void gload16(const unsigned short* g, unsigned short* l) {
  __builtin_amdgcn_global_load_lds(
      (const __attribute__((address_space(1))) void*)(g),
      (__attribute__((address_space(3))) void*)(l), 16, 0, 0);
}

// XOR chunk swizzle for the gathered A tile [128 rows][32 k] bf16.
__device__ __forceinline__ int frag_off(int r, int g) {
  return r * 32 + ((g ^ ((r >> 1) & 3)) << 3);
}

// ---- ws layout ----
constexpr size_t XBF_OFF  = 0;                                       // 8 MB
constexpr size_t HBUF_OFF = (size_t)T_TOKENS * HID * 2;              // 32 MB
constexpr size_t TOKE_OFF = HBUF_OFF + (size_t)T_TOKENS * 2 * FFN * 2;
constexpr size_t TOKW_OFF = TOKE_OFF + (size_t)T_TOKENS * 2 * 4;
constexpr size_t CNT_OFF  = TOKW_OFF + (size_t)T_TOKENS * 2 * 4;
constexpr size_t OFF_OFF  = CNT_OFF + 64;
constexpr size_t LIST_OFF = OFF_OFF + 64;
constexpr size_t META_END = LIST_OFF + (size_t)NE * T_TOKENS * 4;    // ~40.2 MB
constexpr size_t PB1_OFF  = META_END;                                // 32 MB (ybuf reuses)
constexpr size_t PB2_OFF  = PB1_OFF + (size_t)NE * FFN * HID * 2;    // 32 MB
constexpr size_t PW2_OFF  = PB2_OFF + (size_t)NE * FFN * HID * 2;    // 32 MB
constexpr size_t WS_BIG   = PW2_OFF + (size_t)NE * HID * FFN * 2;    // ~136.2 MB
constexpr size_t YBUF_OFF = PB1_OFF;   // ybuf [8192][HID] bf16 = 16 MB; pb1 dead after gemm1

// ==== merged kernel 1: pack_w1v1 (z<16) + router (z==16). grid (128, 8, 17) x 256 ====
__global__ __launch_bounds__(256) void pack_router_kernel(
    const float* __restrict__ w1, const float* __restrict__ v1,
    unsigned short* __restrict__ pb1, unsigned short* __restrict__ pb2,
    const float* __restrict__ x, const float* __restrict__ rw,
    int* __restrict__ tok_e, float* __restrict__ tok_w,
    unsigned short* __restrict__ xbf) {
  __shared__ float smem[NE * HID];   // 32 KB; pack role uses first 4 KB as u16
  int z = blockIdx.z;
  int t = threadIdx.x;
  if (z < 2 * NE) {
    // ---- pack w1/v1 into [e][col/16][k/32][512] (validated r8/r9) ----
    unsigned short* lds = (unsigned short*)smem;
    int colblk = blockIdx.x;            // 0..127 (FFN/16)
    int kslab  = blockIdx.y;            // 0..7   (HID/128)
    const float* src = (z < NE) ? w1 : v1;
    unsigned short* dst = (z < NE) ? pb1 : pb2;
    int e = z & (NE - 1);
    int c  = colblk * 16 + (t >> 4);
    int k0 = kslab * 128 + (t & 15) * 8;
    const float* sp = src + ((size_t)e * FFN + c) * HID + k0;
    float4 a = *(const float4*)sp;
    float4 b = *(const float4*)(sp + 4);
    uint4 o;
    o.x = pack2(a.x, a.y); o.y = pack2(a.z, a.w);
    o.z = pack2(b.x, b.y); o.w = pack2(b.z, b.w);
    int chunk = ((t & 15) >> 2) * 64 + ((t & 3) * 16 + (t >> 4));
    int pos = chunk ^ ((chunk >> 4) & 15);
    *(uint4*)(lds + pos * 8) = o;
    __syncthreads();
    int rpos = t ^ ((t >> 4) & 15);
    uint4 v = *(const uint4*)(lds + rpos * 8);
    unsigned short* dp = dst + (((size_t)e * (FFN / 16) + colblk) * (HID / 32) + kslab * 4) * 512 + t * 8;
    *(uint4*)dp = v;
    return;
  }
  // ---- router (+ fused x->bf16 cast), vectorized; rblk = 0..1023 ----
  float* s_rw = smem;
  for (int i = t; i < NE * HID / 4; i += 256)
    ((float4*)s_rw)[i] = ((const float4*)rw)[i];
  __syncthreads();
  int rblk = blockIdx.x * 8 + blockIdx.y;
  int wave = t >> 6, lane = t & 63;
  int tok = rblk * 4 + wave;
  const float* xr = x + (size_t)tok * HID;
  unsigned short* xbr = xbf + (size_t)tok * HID;
  float acc[NE];
#pragma unroll
  for (int e = 0; e < NE; ++e) acc[e] = 0.0f;
#pragma unroll
  for (int c = 0; c < HID / 256; ++c) {     // 4 iters, 4 elems/lane each
    int idx = c * 256 + lane * 4;
    float4 xv = *(const float4*)(xr + idx);
    uint2 pk; pk.x = pack2(xv.x, xv.y); pk.y = pack2(xv.z, xv.w);
    *(uint2*)(xbr + idx) = pk;              // fused bf16 cast
#pragma unroll
    for (int e = 0; e < NE; ++e) {
      float4 rv = *(const float4*)(s_rw + e * HID + idx);
      acc[e] += xv.x * rv.x + xv.y * rv.y + xv.z * rv.z + xv.w * rv.w;
    }
  }
#pragma unroll
  for (int e = 0; e < NE; ++e)
    for (int off = 32; off > 0; off >>= 1) acc[e] += __shfl_down(acc[e], off);
  if (lane == 0) {
    float m = acc[0];
#pragma unroll
    for (int e = 1; e < NE; ++e) m = fmaxf(m, acc[e]);
    float p[NE], Z = 0.0f;
#pragma unroll
    for (int e = 0; e < NE; ++e) { p[e] = expf(acc[e] - m); Z += p[e]; }
    int e0 = 0;
#pragma unroll
    for (int e = 1; e < NE; ++e) if (p[e] > p[e0]) e0 = e;
    int e1 = (e0 == 0) ? 1 : 0;
#pragma unroll
    for (int e = 0; e < NE; ++e) if (e != e0 && p[e] > p[e1]) e1 = e;
    float w0 = p[e0] / Z, w1 = p[e1] / Z;
    float nrm = w0 + w1;  // P_NORM = 1
    tok_e[tok * 2] = e0; tok_e[tok * 2 + 1] = e1;
    tok_w[tok * 2] = w0 / nrm; tok_w[tok * 2 + 1] = w1 / nrm;
  }
}

// ---- standalone router (fallback path only) ----
__global__ __launch_bounds__(256) void router_kernel(const float* __restrict__ x,
                                                     const float* __restrict__ rw,
                                                     int* __restrict__ tok_e,
                                                     float* __restrict__ tok_w,
                                                     unsigned short* __restrict__ xbf) {
  __shared__ float s_rw[NE * HID];
  int tid = threadIdx.x;
  for (int i = tid; i < NE * HID / 4; i += 256)
    ((float4*)s_rw)[i] = ((const float4*)rw)[i];
  __syncthreads();
  int wave = tid >> 6, lane = tid & 63;
  int t = blockIdx.x * 4 + wave;
  const float* xr = x + (size_t)t * HID;
  unsigned short* xbr = xbf + (size_t)t * HID;
  float acc[NE];
#pragma unroll
  for (int e = 0; e < NE; ++e) acc[e] = 0.0f;
#pragma unroll
  for (int c = 0; c < HID / 256; ++c) {
    int idx = c * 256 + lane * 4;
    float4 xv = *(const float4*)(xr + idx);
    uint2 pk; pk.x = pack2(xv.x, xv.y); pk.y = pack2(xv.z, xv.w);
    *(uint2*)(xbr + idx) = pk;
#pragma unroll
    for (int e = 0; e < NE; ++e) {
      float4 rv = *(const float4*)(s_rw + e * HID + idx);
      acc[e] += xv.x * rv.x + xv.y * rv.y + xv.z * rv.z + xv.w * rv.w;
    }
  }
#pragma unroll
  for (int e = 0; e < NE; ++e)
    for (int off = 32; off > 0; off >>= 1) acc[e] += __shfl_down(acc[e], off);
  if (lane == 0) {
    float m = acc[0];
#pragma unroll
    for (int e = 1; e < NE; ++e) m = fmaxf(m, acc[e]);
    float p[NE], Z = 0.0f;
#pragma unroll
    for (int e = 0; e < NE; ++e) { p[e] = expf(acc[e] - m); Z += p[e]; }
    int e0 = 0;
#pragma unroll
    for (int e = 1; e < NE; ++e) if (p[e] > p[e0]) e0 = e;
    int e1 = (e0 == 0) ? 1 : 0;
#pragma unroll
    for (int e = 0; e < NE; ++e) if (e != e0 && p[e] > p[e1]) e1 = e;
    float w0 = p[e0] / Z, w1 = p[e1] / Z;
    float nrm = w0 + w1;
    tok_e[t * 2] = e0; tok_e[t * 2 + 1] = e1;
    tok_w[t * 2] = w0 / nrm; tok_w[t * 2 + 1] = w1 / nrm;
  }
}

// ---- merged scatter + offsets (single block; LDS counters) ----
__global__ __launch_bounds__(1024) void scatter_offsets_kernel(
    const int* __restrict__ tok_e, int* __restrict__ counts,
    int* __restrict__ offs, int* __restrict__ lists) {
  __shared__ int c[NE];
  int tid = threadIdx.x;
  if (tid < NE) c[tid] = 0;
  __syncthreads();
  for (int p = tid; p < T_TOKENS * 2; p += 1024) {
    int e = tok_e[p];
    int pos = atomicAdd(&c[e], 1);
    lists[e * T_TOKENS + pos] = p;
  }
  __syncthreads();
  if (tid == 0) {
    int r = 0;
    for (int e = 0; e < NE; ++e) { counts[e] = c[e]; offs[e] = r; r += c[e]; }
  }
}

// ---- combine: out[t] = y[2t] + y[2t+1], ybuf is bf16 ----
__global__ __launch_bounds__(256) void combine_kernel(const unsigned short* __restrict__ ybuf,
                                                      float* __restrict__ out) {
  int t = blockIdx.x;
  int c = threadIdx.x;
  uint2 ua = *(const uint2*)(ybuf + (size_t)(2 * t) * HID + c * 4);
  uint2 ub = *(const uint2*)(ybuf + (size_t)(2 * t + 1) * HID + c * 4);
  float4 r;
  r.x = bf2f(ua.x & 0xffff) + bf2f(ub.x & 0xffff);
  r.y = bf2f(ua.x >> 16)    + bf2f(ub.x >> 16);
  r.z = bf2f(ua.y & 0xffff) + bf2f(ub.y & 0xffff);
  r.w = bf2f(ua.y >> 16)    + bf2f(ub.y >> 16);
  ((float4*)(out + (size_t)t * HID))[c] = r;
}

// ==== merged kernel 2: gemm1 (z<8) + pack_w2 (z>=8). grid (16, 32, 16) x 512 ====
// gemm role: r9/r11-exact 2-phase. A swizzled-LDS, B1 packed->LDS, B2 packed->regs.
// pack role: w2 [e][k][c] f32 -> [e][c/16][k/32][512] bf16, 512-thr variant;
// HBM-bound pack blocks overlap the compute-bound gemm blocks in one dispatch.
__global__ __launch_bounds__(512) void gemm1_packw2_kernel(
    const unsigned short* __restrict__ xbf,
    const unsigned short* __restrict__ pb1, const unsigned short* __restrict__ pb2,
    const int* __restrict__ counts, const int* __restrict__ offs,
    const int* __restrict__ lists, unsigned short* __restrict__ hbuf,
    const float* __restrict__ w2, unsigned short* __restrict__ pw2) {
  constexpr int ABUF = 128 * 32;   // 8 KB
  constexpr int BBUF = 128 * 32;   // 8 KB
  constexpr int NT = HID / 32;     // 32 (even)
  __shared__ unsigned short s_a[2 * ABUF];
  __shared__ unsigned short s_b1[2 * BBUF];
  int z = blockIdx.z;
  int tid = threadIdx.x;

  if (z >= NE) {
    // ---------- pack_w2 role ----------
    unsigned short (*s)[68] = (unsigned short (*)[68])s_a;  // 64*68*2B = 8.7 KB
    int e2 = z - NE;
    int cb = blockIdx.x;   // 0..15 (HID/64)
    int kb = blockIdx.y;   // 0..31 (FFN/64)
    const float* src = w2 + ((size_t)e2 * FFN + kb * 64) * HID + cb * 64;
#pragma unroll
    for (int i = 0; i < 2; ++i) {
      int fid = tid + i * 512;          // 0..1023 (64 rows x 16 float4)
      int k = fid >> 4;
      int c4 = (fid & 15) * 4;
      float4 v = *(const float4*)(src + (size_t)k * HID + c4);
      s[k][c4 + 0] = f2bf(v.x); s[k][c4 + 1] = f2bf(v.y);
      s[k][c4 + 2] = f2bf(v.z); s[k][c4 + 3] = f2bf(v.w);
    }
    __syncthreads();
    int colblk_l = tid >> 7, ks_l = (tid >> 6) & 1, lane = tid & 63;
    unsigned short tmp[8];
#pragma unroll
    for (int j = 0; j < 8; ++j)
      tmp[j] = s[ks_l * 32 + (lane >> 4) * 8 + j][colblk_l * 16 + (lane & 15)];
    uint4 o;
    o.x = tmp[0] | (tmp[1] << 16); o.y = tmp[2] | (tmp[3] << 16);
    o.z = tmp[4] | (tmp[5] << 16); o.w = tmp[6] | (tmp[7] << 16);
    unsigned short* dp = pw2 + (((size_t)e2 * (HID / 16) + cb * 4 + colblk_l) * (FFN / 32)
                                + kb * 2 + ks_l) * 512 + lane * 8;
    *(uint4*)dp = o;
    return;
  }

  // ---------- gemm1 role (r11-exact) ----------
  int nt = blockIdx.x, mt = blockIdx.y, e = z;
  int ne = counts[e];
  if (mt * 128 >= ne) return;
  int srow = tid >> 2, slot = tid & 3;
  int lchunk = slot ^ ((srow >> 1) & 3);
  const int* lst = lists + e * T_TOKENS + mt * 128;
  int tok = lst[(mt * 128 + srow < ne) ? srow : 0] >> 1;
  const unsigned short* aptr = xbf + (size_t)tok * HID + lchunk * 8;
  int g8 = tid >> 6, ln = tid & 63;
  const unsigned short* b1p =
      pb1 + ((size_t)(e * (FFN / 16) + nt * 8 + g8) * (HID / 32)) * 512 + ln * 8;

  int lane = tid & 63, wv = tid >> 6;
  int wm = (wv >> 2) * 64, wn = (wv & 3) * 32;
  int rl = lane & 15, g = lane >> 4;
  int aoff[4];
#pragma unroll
  for (int m = 0; m < 4; ++m) aoff[m] = frag_off(wm + m * 16 + rl, g);
  int b1off[2];
#pragma unroll
  for (int n = 0; n < 2; ++n) b1off[n] = (((wv & 3) * 2 + n) * 64 + lane) * 8;
  size_t cb2 = (size_t)e * (FFN / 16) + nt * 8 + (wv & 3) * 2;
  const unsigned short* p2_0 = pb2 + (cb2 + 0) * (HID / 32) * 512 + lane * 8;
  const unsigned short* p2_1 = pb2 + (cb2 + 1) * (HID / 32) * 512 + lane * 8;

  f32x4 zero = {0.0f, 0.0f, 0.0f, 0.0f};
  f32x4 acc1[4][2], acc2[4][2];
#pragma unroll
  for (int i = 0; i < 4; ++i)
#pragma unroll
    for (int j = 0; j < 2; ++j) { acc1[i][j] = zero; acc2[i][j] = zero; }

  auto stage = [&](int s, int t) {   // s literal -> const-folded
    gload16(aptr + t * 32, s_a + s * ABUF + tid * 8);
    gload16(b1p + (size_t)t * 512, s_b1 + s * BBUF + tid * 8);
  };
  bf16x8 b2X[2], b2Y[2];
  auto loadBX = [&](int t) {
    b2X[0] = *(const bf16x8*)(p2_0 + (size_t)t * 512);
    b2X[1] = *(const bf16x8*)(p2_1 + (size_t)t * 512);
  };
  auto loadBY = [&](int t) {
    b2Y[0] = *(const bf16x8*)(p2_0 + (size_t)t * 512);
    b2Y[1] = *(const bf16x8*)(p2_1 + (size_t)t * 512);
  };
  auto compute = [&](int s, bf16x8 (&b2)[2]) {
    const unsigned short* pa = s_a + s * ABUF;
    const unsigned short* pb = s_b1 + s * BBUF;
    bf16x8 af[4], bf1[2];
#pragma unroll
    for (int m = 0; m < 4; ++m) af[m] = *(const bf16x8*)(pa + aoff[m]);
#pragma unroll
    for (int n = 0; n < 2; ++n) bf1[n] = *(const bf16x8*)(pb + b1off[n]);
#pragma unroll
    for (int m = 0; m < 4; ++m)
#pragma unroll
      for (int n = 0; n < 2; ++n) {
        acc1[m][n] = __builtin_amdgcn_mfma_f32_16x16x32_bf16(af[m], bf1[n], acc1[m][n], 0, 0, 0);
        acc2[m][n] = __builtin_amdgcn_mfma_f32_16x16x32_bf16(af[m], b2[n], acc2[m][n], 0, 0, 0);
      }
  };

  stage(0, 0);
  loadBX(0);
  __syncthreads();
  for (int t = 0; t < NT; t += 2) {
    stage(1, t + 1);
    loadBY(t + 1);
    compute(0, b2X);
    __syncthreads();
    if (t + 2 < NT) { stage(0, t + 2); loadBX(t + 2); }
    compute(1, b2Y);
    __syncthreads();
  }

  int hb = offs[e];
#pragma unroll
  for (int m = 0; m < 4; ++m) {
#pragma unroll
    for (int j = 0; j < 4; ++j) {
      int r = mt * 128 + wm + m * 16 + (lane >> 4) * 4 + j;
      if (r < ne) {
        size_t rowo = (size_t)(hb + r) * FFN;
#pragma unroll
        for (int n = 0; n < 2; ++n) {
          int col = nt * 128 + wn + n * 16 + rl;
          float c1 = acc1[m][n][j], c2 = acc2[m][n][j];
          float h = c1 / (1.0f + __expf(-c1)) * c2;
          hbuf[rowo + col] = f2bf(h);
        }
      }
    }
  }
}

// ========== GEMM2: A via LDS, B from packed global (reg dbuf); bf16 ybuf stores ======
__global__ __launch_bounds__(512) void gemm2b_kernel(
    const unsigned short* __restrict__ hbuf, const unsigned short* __restrict__ pw2,
    const int* __restrict__ counts, const int* __restrict__ offs,
    const int* __restrict__ lists, const float* __restrict__ tok_w,
    unsigned short* __restrict__ ybuf) {
  constexpr int BUFSZ = 128 * 32;
  constexpr int NT = FFN / 32;
  int nt = blockIdx.x, mt = blockIdx.y, e = blockIdx.z;
  int ne = counts[e];
  if (mt * 128 >= ne) return;
  __shared__ unsigned short s_a[2 * BUFSZ];
  int tid = threadIdx.x;
  int hb = offs[e];
  int srow = tid >> 2, slot = tid & 3;
  int lchunk = slot ^ ((srow >> 1) & 3);
  int ar = mt * 128 + ((mt * 128 + srow < ne) ? srow : 0);
  const unsigned short* aptr = hbuf + (size_t)(hb + ar) * FFN + lchunk * 8;

  int lane = tid & 63, wv = tid >> 6;
  int wm = (wv >> 2) * 64, wn = (wv & 3) * 32;
  int rl = lane & 15, g = lane >> 4;
  int aoff[4];
#pragma unroll
  for (int m = 0; m < 4; ++m) aoff[m] = frag_off(wm + m * 16 + rl, g);

  size_t cb = (size_t)e * (HID / 16) + nt * 8 + (wv & 3) * 2;
  const unsigned short* p_0 = pw2 + (cb + 0) * (FFN / 32) * 512 + lane * 8;
  const unsigned short* p_1 = pw2 + (cb + 1) * (FFN / 32) * 512 + lane * 8;

  f32x4 zero = {0.0f, 0.0f, 0.0f, 0.0f};
  f32x4 acc[4][2];
#pragma unroll
  for (int i = 0; i < 4; ++i)
#pragma unroll
    for (int j = 0; j < 2; ++j) acc[i][j] = zero;

  auto stageA = [&](int s, int t) {
    gload16(aptr + t * 32, s_a + s * BUFSZ + tid * 8);
  };
  bf16x8 bX[2], bY[2];
  auto loadBX = [&](int t) {
    bX[0] = *(const bf16x8*)(p_0 + (size_t)t * 512);
    bX[1] = *(const bf16x8*)(p_1 + (size_t)t * 512);
  };
  auto loadBY = [&](int t) {
    bY[0] = *(const bf16x8*)(p_0 + (size_t)t * 512);
    bY[1] = *(const bf16x8*)(p_1 + (size_t)t * 512);
  };
  auto compute = [&](int s, bf16x8 (&b)[2]) {
    const unsigned short* pa = s_a + s * BUFSZ;
    bf16x8 af[4];
#pragma unroll
    for (int m = 0; m < 4; ++m) af[m] = *(const bf16x8*)(pa + aoff[m]);
#pragma unroll
    for (int m = 0; m < 4; ++m)
#pragma unroll
      for (int n = 0; n < 2; ++n)
        acc[m][n] = __builtin_amdgcn_mfma_f32_16x16x32_bf16(af[m], b[n], acc[m][n], 0, 0, 0);
  };

  stageA(0, 0);
  loadBX(0);
  __syncthreads();
  for (int t = 0; t < NT; t += 2) {
    stageA(1, t + 1);
    loadBY(t + 1);
    compute(0, bX);
    __syncthreads();
    if (t + 2 < NT) { stageA(0, t + 2); loadBX(t + 2); }
    compute(1, bY);
    __syncthreads();
  }

#pragma unroll
  for (int m = 0; m < 4; ++m) {
#pragma unroll
    for (int j = 0; j < 4; ++j) {
      int r = mt * 128 + wm + m * 16 + (lane >> 4) * 4 + j;
      if (r < ne) {
        int p = lists[e * T_TOKENS + r];
        float w = tok_w[p];
        unsigned short* yrow = ybuf + (size_t)p * HID;
#pragma unroll
        for (int n = 0; n < 2; ++n) {
          int col = nt * 128 + wn + n * 16 + rl;
          yrow[col] = f2bf(acc[m][n][j] * w);
        }
      }
    }
  }
}

// ================= fallback path (ws too small): proven round-2 kernels ======

__global__ __launch_bounds__(512) void gemm1_kernel(
    const unsigned short* __restrict__ xbf,
    const float* __restrict__ w1, const float* __restrict__ v1,
    const int* __restrict__ counts, const int* __restrict__ offs,
    const int* __restrict__ lists, unsigned short* __restrict__ hbuf) {
  int nt = blockIdx.x, mt = blockIdx.y, e = blockIdx.z;
  int ne = counts[e];
  if (mt * 128 >= ne) return;
  int nrows = ne - mt * 128; if (nrows > 128) nrows = 128;
  __shared__ unsigned short s_a[128 * 40];
  __shared__ unsigned short s_b1[128 * 40];
  __shared__ unsigned short s_b2[128 * 40];
  const int* lst = lists + e * T_TOKENS + mt * 128;
  int tid = threadIdx.x;
  int sr = tid >> 2, sc = tid & 3;
  int pr = lst[(sr < nrows) ? sr : 0];
  const unsigned short* asrc = xbf + (size_t)(pr >> 1) * HID + sc * 8;
  size_t brow = ((size_t)e * FFN + nt * 128 + sr) * HID + sc * 8;
  const float* b1s = w1 + brow;
  const float* b2s = v1 + brow;
  int lane = tid & 63, wv = tid >> 6;
  int wm = (wv >> 2) * 64, wn = (wv & 3) * 32;
  int rl = lane & 15, kg = (lane >> 4) * 8;
  f32x4 zero = {0.0f, 0.0f, 0.0f, 0.0f};
  f32x4 acc1[4][2], acc2[4][2];
#pragma unroll
  for (int i = 0; i < 4; ++i)
#pragma unroll
    for (int j = 0; j < 2; ++j) { acc1[i][j] = zero; acc2[i][j] = zero; }
  int sdst = sr * 40 + sc * 8;
  for (int kk = 0; kk < HID; kk += 32) {
    uint4 av = *(const uint4*)(asrc + kk);
    float4 f0 = *(const float4*)(b1s + kk);
    float4 f1 = *(const float4*)(b1s + kk + 4);
    float4 g0 = *(const float4*)(b2s + kk);
    float4 g1 = *(const float4*)(b2s + kk + 4);
    *(uint4*)(s_a + sdst) = av;
    uint4 bv; bv.x = pack2(f0.x, f0.y); bv.y = pack2(f0.z, f0.w);
    bv.z = pack2(f1.x, f1.y); bv.w = pack2(f1.z, f1.w);
    *(uint4*)(s_b1 + sdst) = bv;
    uint4 cv; cv.x = pack2(g0.x, g0.y); cv.y = pack2(g0.z, g0.w);
    cv.z = pack2(g1.x, g1.y); cv.w = pack2(g1.z, g1.w);
    *(uint4*)(s_b2 + sdst) = cv;
    __syncthreads();
    bf16x8 af[4], bf1[2], bf2[2];
#pragma unroll
    for (int m = 0; m < 4; ++m)
      af[m] = *(const bf16x8*)(s_a + (wm + m * 16 + rl) * 40 + kg);
#pragma unroll
    for (int n = 0; n < 2; ++n) {
      bf1[n] = *(const bf16x8*)(s_b1 + (wn + n * 16 + rl) * 40 + kg);
      bf2[n] = *(const bf16x8*)(s_b2 + (wn + n * 16 + rl) * 40 + kg);
    }
#pragma unroll
    for (int m = 0; m < 4; ++m)
#pragma unroll
      for (int n = 0; n < 2; ++n) {
        acc1[m][n] = __builtin_amdgcn_mfma_f32_16x16x32_bf16(af[m], bf1[n], acc1[m][n], 0, 0, 0);
        acc2[m][n] = __builtin_amdgcn_mfma_f32_16x16x32_bf16(af[m], bf2[n], acc2[m][n], 0, 0, 0);
      }
    __syncthreads();
  }
  int hb = offs[e];
#pragma unroll
  for (int m = 0; m < 4; ++m) {
#pragma unroll
    for (int j = 0; j < 4; ++j) {
      int r = mt * 128 + wm + m * 16 + (lane >> 4) * 4 + j;
      if (r < ne) {
        size_t rowo = (size_t)(hb + r) * FFN;
#pragma unroll
        for (int n = 0; n < 2; ++n) {
          int col = nt * 128 + wn + n * 16 + rl;
          float c1 = acc1[m][n][j], c2 = acc2[m][n][j];
          float h = c1 / (1.0f + __expf(-c1)) * c2;
          hbuf[rowo + col] = f2bf(h);
        }
      }
    }
  }
}

__global__ __launch_bounds__(512) void gemm2_kernel(
    const unsigned short* __restrict__ hbuf, const float* __restrict__ w2,
    const int* __restrict__ counts, const int* __restrict__ offs,
    const int* __restrict__ lists, const float* __restrict__ tok_w,
    float* __restrict__ out) {
  int nt = blockIdx.x, mt = blockIdx.y, e = blockIdx.z;
  int ne = counts[e];
  if (mt * 128 >= ne) return;
  int nrows = ne - mt * 128; if (nrows > 128) nrows = 128;
  __shared__ unsigned short s_a[128 * 40];
  __shared__ unsigned short s_b[128 * 40];
  int tid = threadIdx.x;
  int hb = offs[e];
  int sr = tid >> 2, sc = tid & 3;
  int ar = mt * 128 + ((sr < nrows) ? sr : 0);
  const unsigned short* asrc = hbuf + (size_t)(hb + ar) * FFN + sc * 8;
  int bk = tid >> 4, bn = tid & 15;
  const float* bsrc = w2 + ((size_t)e * FFN + bk) * HID + nt * 128 + bn;
  int lane = tid & 63, wv = tid >> 6;
  int wm = (wv >> 2) * 64, wn = (wv & 3) * 32;
  int rl = lane & 15, kg = (lane >> 4) * 8;
  f32x4 zero = {0.0f, 0.0f, 0.0f, 0.0f};
  f32x4 acc[4][2];
#pragma unroll
  for (int i = 0; i < 4; ++i)
#pragma unroll
    for (int j = 0; j < 2; ++j) acc[i][j] = zero;
  int sdst = sr * 40 + sc * 8;
  for (int kk = 0; kk < FFN; kk += 32) {
    uint4 av = *(const uint4*)(asrc + kk);
    const float* bs = bsrc + (size_t)kk * HID;
    float bvals[8];
#pragma unroll
    for (int i = 0; i < 8; ++i) bvals[i] = bs[i * 16];
    *(uint4*)(s_a + sdst) = av;
#pragma unroll
    for (int i = 0; i < 8; ++i) s_b[(bn + i * 16) * 40 + bk] = f2bf(bvals[i]);
    __syncthreads();
    bf16x8 af[4], bfr[2];
#pragma unroll
    for (int m = 0; m < 4; ++m)
      af[m] = *(const bf16x8*)(s_a + (wm + m * 16 + rl) * 40 + kg);
#pragma unroll
    for (int n = 0; n < 2; ++n)
      bfr[n] = *(const bf16x8*)(s_b + (wn + n * 16 + rl) * 40 + kg);
#pragma unroll
    for (int m = 0; m < 4; ++m)
#pragma unroll
      for (int n = 0; n < 2; ++n)
        acc[m][n] = __builtin_amdgcn_mfma_f32_16x16x32_bf16(af[m], bfr[n], acc[m][n], 0, 0, 0);
    __syncthreads();
  }
#pragma unroll
  for (int m = 0; m < 4; ++m) {
#pragma unroll
    for (int j = 0; j < 4; ++j) {
      int r = mt * 128 + wm + m * 16 + (lane >> 4) * 4 + j;
      if (r < ne) {
        int p = lists[e * T_TOKENS + r];
        float w = tok_w[p];
        float* orow = out + (size_t)(p >> 1) * HID;
#pragma unroll
        for (int n = 0; n < 2; ++n) {
          int col = nt * 128 + wn + n * 16 + rl;
          atomicAdd(orow + col, acc[m][n][j] * w);
        }
      }
    }
  }
}

extern "C" void kernel_launch(void* const* d_in, const int* in_sizes, int n_in,
                              void* d_out, int out_size, void* d_ws, size_t ws_size,
                              hipStream_t stream) {
  const float* x  = (const float*)d_in[0];
  const float* rw = (const float*)d_in[1];
  const float* w1 = (const float*)d_in[2];
  const float* v1 = (const float*)d_in[3];
  const float* w2 = (const float*)d_in[4];
  float* out = (float*)d_out;
  char* ws = (char*)d_ws;
  if (ws_size < META_END) return;

  unsigned short* xbf  = (unsigned short*)(ws + XBF_OFF);
  unsigned short* hbuf = (unsigned short*)(ws + HBUF_OFF);
  int*   tok_e  = (int*)(ws + TOKE_OFF);
  float* tok_w  = (float*)(ws + TOKW_OFF);
  int*   counts = (int*)(ws + CNT_OFF);
  int*   offs   = (int*)(ws + OFF_OFF);
  int*   lists  = (int*)(ws + LIST_OFF);

  if (ws_size >= WS_BIG) {
    unsigned short* pb1 = (unsigned short*)(ws + PB1_OFF);
    unsigned short* pb2 = (unsigned short*)(ws + PB2_OFF);
    unsigned short* pw2 = (unsigned short*)(ws + PW2_OFF);
    unsigned short* ybuf = (unsigned short*)(ws + YBUF_OFF);  // overlaps pb1 (dead after gemm1)
    // pack_w1v1 + router in one dispatch (independent roles)
    pack_router_kernel<<<dim3(FFN / 16, HID / 128, 2 * NE + 1), 256, 0, stream>>>(
        w1, v1, pb1, pb2, x, rw, tok_e, tok_w, xbf);
    scatter_offsets_kernel<<<1, 1024, 0, stream>>>(tok_e, counts, offs, lists);
    // gemm1 + pack_w2 in one dispatch (pack fills gemm's memory bubbles)
    gemm1_packw2_kernel<<<dim3(FFN / 128, T_TOKENS / 128, 2 * NE), 512, 0, stream>>>(
        xbf, pb1, pb2, counts, offs, lists, hbuf, w2, pw2);
    gemm2b_kernel<<<dim3(HID / 128, T_TOKENS / 128, NE), 512, 0, stream>>>(
        hbuf, pw2, counts, offs, lists, tok_w, ybuf);
    combine_kernel<<<T_TOKENS, 256, 0, stream>>>(ybuf, out);
  } else {
    router_kernel<<<T_TOKENS / 4, 256, 0, stream>>>(x, rw, tok_e, tok_w, xbf);
    scatter_offsets_kernel<<<1, 1024, 0, stream>>>(tok_e, counts, offs, lists);
    hipMemsetAsync(d_out, 0, (size_t)T_TOKENS * HID * 4, stream);
    gemm1_kernel<<<dim3(FFN / 128, T_TOKENS / 128, NE), 512, 0, stream>>>(
        xbf, w1, v1, counts, offs, lists, hbuf);
    gemm2_kernel<<<dim3(HID / 128, T_TOKENS / 128, NE), 512, 0, stream>>>(
        hbuf, w2, counts, offs, lists, tok_w, out);
  }
}